// Round 16
// baseline (30.937 us; speedup 1.0000x reference)
//
#include <hip/hip_runtime.h>

#define NF 39
#define NE 40
#define NB 4096
#define NSLOT 1536            // 6 tiles * 256 MFMA slots (stats space)
#define NBLK 1024             // k1/k3 blocks: 4 samples/block, 1 per wave
#define SPB 4
#define K2_BLOCKS 48          // 48 * 32 slots = 1536
#define K2_ROWS 128           // 1024 partial rows / 8 row-groups
#define EPS 1.0e-3f

typedef __attribute__((ext_vector_type(8))) short short8;
typedef __attribute__((ext_vector_type(4))) float floatx4;

__device__ __forceinline__ unsigned int f2bf(float f) {
    unsigned int b = __float_as_uint(f);
    b += 0x7FFFu + ((b >> 16) & 1u);   // round-to-nearest-even
    return b >> 16;
}

__device__ __forceinline__ float bf2f(unsigned int u) {
    return __uint_as_float(u << 16);
}

__device__ __forceinline__ short8 pack8(float4 a, float4 b) {
    union { unsigned int u[4]; short8 s; } o;
    o.u[0] = f2bf(a.x) | (f2bf(a.y) << 16);
    o.u[1] = f2bf(a.z) | (f2bf(a.w) << 16);
    o.u[2] = f2bf(b.x) | (f2bf(b.y) << 16);
    o.u[3] = f2bf(b.z) | (f2bf(b.w) << 16);
    return o.s;
}

// Direct-to-register fragment gather for one sample (validated R4-R14).
__device__ __forceinline__ void load_frags(
    const int* __restrict__ ip, const float* __restrict__ v,
    int rbase, int ehalf, short8 F0[3], short8 F1[3])
{
    const float4 zero4 = {0.f, 0.f, 0.f, 0.f};
#pragma unroll
    for (int I = 0; I < 3; ++I) {
        const int r = rbase + 16 * I;
        const bool vr = (r < NF);
        const int id = vr ? ip[r] : 0;
        const float* vrow = v + (size_t)id * NE;
        const float4 a  = vr ? *reinterpret_cast<const float4*>(vrow + ehalf * 8)     : zero4;
        const float4 bq = vr ? *reinterpret_cast<const float4*>(vrow + ehalf * 8 + 4) : zero4;
        F0[I] = pack8(a, bq);
        const bool v1 = vr && (ehalf == 0);
        const float4 c_ = v1 ? *reinterpret_cast<const float4*>(vrow + 32) : zero4;
        const float4 d_ = v1 ? *reinterpret_cast<const float4*>(vrow + 36) : zero4;
        F1[I] = pack8(c_, d_);
    }
}

__device__ __forceinline__ void gram_mfma(const short8 F0[3], const short8 F1[3], floatx4 acc[6])
{
    acc[0] = __builtin_amdgcn_mfma_f32_16x16x32_bf16(F0[0], F0[0], acc[0], 0, 0, 0);
    acc[1] = __builtin_amdgcn_mfma_f32_16x16x32_bf16(F0[0], F0[1], acc[1], 0, 0, 0);
    acc[2] = __builtin_amdgcn_mfma_f32_16x16x32_bf16(F0[0], F0[2], acc[2], 0, 0, 0);
    acc[3] = __builtin_amdgcn_mfma_f32_16x16x32_bf16(F0[1], F0[1], acc[3], 0, 0, 0);
    acc[4] = __builtin_amdgcn_mfma_f32_16x16x32_bf16(F0[1], F0[2], acc[4], 0, 0, 0);
    acc[5] = __builtin_amdgcn_mfma_f32_16x16x32_bf16(F0[2], F0[2], acc[5], 0, 0, 0);
    acc[0] = __builtin_amdgcn_mfma_f32_16x16x32_bf16(F1[0], F1[0], acc[0], 0, 0, 0);
    acc[1] = __builtin_amdgcn_mfma_f32_16x16x32_bf16(F1[0], F1[1], acc[1], 0, 0, 0);
    acc[2] = __builtin_amdgcn_mfma_f32_16x16x32_bf16(F1[0], F1[2], acc[2], 0, 0, 0);
    acc[3] = __builtin_amdgcn_mfma_f32_16x16x32_bf16(F1[1], F1[1], acc[3], 0, 0, 0);
    acc[4] = __builtin_amdgcn_mfma_f32_16x16x32_bf16(F1[1], F1[2], acc[4], 0, 0, 0);
    acc[5] = __builtin_amdgcn_mfma_f32_16x16x32_bf16(F1[2], F1[2], acc[5], 0, 0, 0);
}

// ---------------- Kernel 1: gather + Gram -> bf16 G + 24KB two-pass fold + packed partial ----------------
// 1024 blocks x 24.5 KB LDS -> 4 blocks/CU resident, 4 waves/SIMD for gather latency hiding.
__global__ __launch_bounds__(256) void fm_k1(
    const int* __restrict__ inputs, const float* __restrict__ w,
    const float* __restrict__ v, unsigned short* __restrict__ Gb,
    float* __restrict__ lsum, unsigned int* __restrict__ partial)
{
    __shared__ float red[4 * NSLOT];   // 24 KB, two-pass (sum then sumsq)
    const int t = threadIdx.x, wid = t >> 6, lane = t & 63;
    const int rbase = lane & 15, ehalf = lane >> 4;
    const int smp = blockIdx.x * SPB + wid;    // one sample per wave

    const int* ip = inputs + (size_t)smp * NF;
    short8 F0[3], F1[3];
    load_frags(ip, v, rbase, ehalf, F0, F1);

    // first-order term
    float wv = (lane < NF) ? w[ip[lane]] : 0.0f;
#pragma unroll
    for (int o = 32; o > 0; o >>= 1) wv += __shfl_down(wv, o, 64);
    if (lane == 0) lsum[smp] = wv;

    floatx4 acc[6] = {};
    gram_mfma(F0, F1, acc);

    // persist G as bf16, slot-major (8 B/lane coalesced)
    unsigned short* gr = Gb + (size_t)smp * NSLOT;
#pragma unroll
    for (int tl = 0; tl < 6; ++tl) {
        uint2 pk;
        pk.x = f2bf(acc[tl][0]) | (f2bf(acc[tl][1]) << 16);
        pk.y = f2bf(acc[tl][2]) | (f2bf(acc[tl][3]) << 16);
        *reinterpret_cast<uint2*>(gr + tl * 256 + lane * 4) = pk;
    }

    // two-pass cross-wave fold: sum, then sumsq (SPW=1: sum == acc)
    float* rw = &red[wid * NSLOT];
#pragma unroll
    for (int tl = 0; tl < 6; ++tl)
        *reinterpret_cast<floatx4*>(rw + tl * 256 + lane * 4) = acc[tl];
    __syncthreads();
    float sarr[6];
#pragma unroll
    for (int k = 0; k < 6; ++k) {
        const int j = t + 256 * k;
        sarr[k] = red[j] + red[NSLOT + j] + red[2 * NSLOT + j] + red[3 * NSLOT + j];
    }
    __syncthreads();
#pragma unroll
    for (int tl = 0; tl < 6; ++tl)
        *reinterpret_cast<floatx4*>(rw + tl * 256 + lane * 4) = acc[tl] * acc[tl];
    __syncthreads();
    unsigned int* po = partial + (size_t)blockIdx.x * NSLOT;
#pragma unroll
    for (int k = 0; k < 6; ++k) {
        const int j = t + 256 * k;
        const float q = red[j] + red[NSLOT + j] + red[2 * NSLOT + j] + red[3 * NSLOT + j];
        po[j] = (f2bf(sarr[k]) << 16) | f2bf(q);   // sum HIGH, sumsq LOW
    }
}

// ---------------- Kernel 2: column-reduce (1024 rows) + mean/scale finalize ----------------
__global__ __launch_bounds__(256) void fm_k2(
    const unsigned int* __restrict__ partial, const float* __restrict__ ew,
    float* __restrict__ meanArr, float* __restrict__ scaleArr)
{
    const int t = threadIdx.x;
    const int slotL = t & 31, rg = t >> 5;          // 8 row-groups x 128 rows
    const int slot0 = blockIdx.x * 32;
    float s1 = 0.f, s2 = 0.f;
#pragma unroll 8
    for (int r = 0; r < K2_ROWS; ++r) {
        const unsigned int u = partial[(size_t)(rg * K2_ROWS + r) * NSLOT + slot0 + slotL];
        s1 += __uint_as_float(u & 0xFFFF0000u);   // sum (high half)
        s2 += __uint_as_float(u << 16);           // sumsq (low half)
    }
    __shared__ float r1[8][32], r2[8][32];
    r1[rg][slotL] = s1;
    r2[rg][slotL] = s2;
    __syncthreads();
    if (t < 32) {
        float a = 0.f, b = 0.f;
#pragma unroll
        for (int g = 0; g < 8; ++g) { a += r1[g][t]; b += r2[g][t]; }
        const int slot = slot0 + t;
        const float m   = a * (1.0f / NB);
        const float var = b * (1.0f / NB) - m * m;
        const int tile = slot >> 8;
        const int l    = (slot & 255) >> 2;
        const int q    = slot & 3;
        const int TI[6] = {0, 0, 0, 1, 1, 2};
        const int TJ[6] = {0, 1, 2, 1, 2, 2};
        const int gi = 16 * TI[tile] + ((l >> 4) << 2) + q;
        const int gj = 16 * TJ[tile] + (l & 15);
        float scl = 0.0f;
        if (gi < gj && gj < NF) {
            const int p = 38 * gi - (gi * (gi - 1)) / 2 + (gj - gi - 1);
            scl = ew[p] * rsqrtf(var + EPS);
        }
        meanArr[slot]  = m;
        scaleArr[slot] = scl;
    }
}

// ---------------- Kernel 3: stream bf16 G + normalize-reduce + first-order ----------------
__global__ __launch_bounds__(256) void fm_k3(
    const unsigned short* __restrict__ Gb, const float* __restrict__ lsum,
    const float* __restrict__ meanArr, const float* __restrict__ scaleArr,
    const float* __restrict__ bias, float* __restrict__ out)
{
    const int t = threadIdx.x, wid = t >> 6, lane = t & 63;
    const int smp = blockIdx.x * SPB + wid;    // one sample per wave

    floatx4 mf[6], sf[6];
#pragma unroll
    for (int tl = 0; tl < 6; ++tl) {
        mf[tl] = *reinterpret_cast<const floatx4*>(meanArr  + tl * 256 + lane * 4);
        sf[tl] = *reinterpret_cast<const floatx4*>(scaleArr + tl * 256 + lane * 4);
    }
    const unsigned short* gr = Gb + (size_t)smp * NSLOT;
    float tot = (lane == 0) ? (lsum[smp] + bias[0]) : 0.0f;
#pragma unroll
    for (int tl = 0; tl < 6; ++tl) {
        const uint2 pk = *reinterpret_cast<const uint2*>(gr + tl * 256 + lane * 4);
        tot += (bf2f(pk.x & 0xFFFFu) - mf[tl][0]) * sf[tl][0];
        tot += (bf2f(pk.x >> 16)     - mf[tl][1]) * sf[tl][1];
        tot += (bf2f(pk.y & 0xFFFFu) - mf[tl][2]) * sf[tl][2];
        tot += (bf2f(pk.y >> 16)     - mf[tl][3]) * sf[tl][3];
    }
#pragma unroll
    for (int o = 32; o > 0; o >>= 1) tot += __shfl_down(tot, o, 64);
    if (lane == 0) out[smp] = tot;
}

extern "C" void kernel_launch(void* const* d_in, const int* in_sizes, int n_in,
                              void* d_out, int out_size, void* d_ws, size_t ws_size,
                              hipStream_t stream)
{
    const int*   inputs = (const int*)  d_in[0];
    // d_in[1]=rows, d_in[2]=cols reproduced in-kernel (validated R2-R14)
    const float* w      = (const float*)d_in[3];
    const float* v      = (const float*)d_in[4];
    const float* bias   = (const float*)d_in[5];
    const float* ew     = (const float*)d_in[6];
    float*       out    = (float*)      d_out;

    // ws: Gb bf16[4096*1536] | partial u32[1024*1536] | mean f32[1536] | scale f32[1536] | lsum f32[4096]
    unsigned short* Gb = (unsigned short*)d_ws;
    unsigned int* partial = (unsigned int*)(Gb + (size_t)NB * NSLOT);
    float* meanA   = (float*)(partial + (size_t)NBLK * NSLOT);
    float* scaleA  = meanA + NSLOT;
    float* lsum    = scaleA + NSLOT;

    fm_k1<<<NBLK,      256, 0, stream>>>(inputs, w, v, Gb, lsum, partial);
    fm_k2<<<K2_BLOCKS, 256, 0, stream>>>(partial, ew, meanA, scaleA);
    fm_k3<<<NBLK,      256, 0, stream>>>(Gb, lsum, meanA, scaleA, bias, out);
}